// Round 13
// baseline (297.711 us; speedup 1.0000x reference)
//
#include <hip/hip_runtime.h>
#include <math.h>

typedef __attribute__((ext_vector_type(8))) short short8v;   // 8 x bf16 (4 VGPR)
typedef __attribute__((ext_vector_type(4))) float f32x4;     // MFMA acc

__device__ __forceinline__ short bf_hi(float x) {
  union { float f; unsigned u; } c; c.f = x;
  unsigned r = (c.u + 0x7fffu + ((c.u >> 16) & 1u)) >> 16;   // RNE bf16
  return (short)r;
}
__device__ __forceinline__ float bf_f(short h) {
  union { float f; unsigned u; } c; c.u = ((unsigned)(unsigned short)h) << 16;
  return c.f;
}

// ================= CSR build =================

__global__ __launch_bounds__(256) void k_zero_i(int* __restrict__ p, int n) {
  int i = blockIdx.x * 256 + threadIdx.x;
  if (i < n) p[i] = 0;
}

// count degrees AND record each edge's slot within its dst bucket (coalesced write)
__global__ __launch_bounds__(256) void k_count(int* __restrict__ cnt,
                                               int* __restrict__ sl,
                                               const int* __restrict__ dst, int E) {
  int e = blockIdx.x * 256 + threadIdx.x;
  if (e < E) sl[e] = atomicAdd(&cnt[dst[e]], 1);
}

constexpr int SCI = 8, SCCH = 2048;  // 256 threads * 8 items

__global__ __launch_bounds__(256) void k_scan1(const int* __restrict__ cnt,
                                               int* __restrict__ rp,
                                               int* __restrict__ bsum, int n) {
  __shared__ int sh[256];
  int tid = threadIdx.x;
  int base = blockIdx.x * SCCH + tid * SCI;
  int v[SCI];
  int s = 0;
#pragma unroll
  for (int i = 0; i < SCI; ++i) { int idx = base + i; v[i] = (idx < n) ? cnt[idx] : 0; s += v[i]; }
  sh[tid] = s;
  __syncthreads();
  for (int off = 1; off < 256; off <<= 1) {
    int t = (tid >= off) ? sh[tid - off] : 0;
    __syncthreads();
    sh[tid] += t;
    __syncthreads();
  }
  int excl = sh[tid] - s;
  if (tid == 255) bsum[blockIdx.x] = sh[255];
  int run = excl;
#pragma unroll
  for (int i = 0; i < SCI; ++i) { int idx = base + i; if (idx < n) rp[idx] = run; run += v[i]; }
}

__global__ __launch_bounds__(256) void k_scan2(int* __restrict__ bsum, int nb) {
  __shared__ int sh[256];
  int tid = threadIdx.x;
  int s = (tid < nb) ? bsum[tid] : 0;
  sh[tid] = s;
  __syncthreads();
  for (int off = 1; off < 256; off <<= 1) {
    int t = (tid >= off) ? sh[tid - off] : 0;
    __syncthreads();
    sh[tid] += t;
    __syncthreads();
  }
  if (tid < nb) bsum[tid] = sh[tid] - s;  // exclusive
}

// rp finalize + dinv, fused
__global__ __launch_bounds__(256) void k_scan3(int* __restrict__ rp,
                                               const int* __restrict__ bsum,
                                               const int* __restrict__ cnt_in,
                                               float* __restrict__ dinv,
                                               int n, int Etot) {
  int i = blockIdx.x * 256 + threadIdx.x;
  if (i < n) {
    rp[i] = rp[i] + bsum[i / SCCH];
    dinv[i] = rsqrtf(1.0f + (float)cnt_in[i]);  // +1 self-loop
  }
  if (i == 0) rp[n] = Etot;
}

// fill csr entries (src, w) with no atomics: pos = rp[dst] + slot
__global__ __launch_bounds__(256) void k_fill(const int* __restrict__ src,
                                              const int* __restrict__ dst,
                                              const int* __restrict__ sl,
                                              const int* __restrict__ rp,
                                              const float* __restrict__ dinv,
                                              int2* __restrict__ csr, int E) {
  int e = blockIdx.x * 256 + threadIdx.x;
  if (e >= E) return;
  int s = src[e], d = dst[e];
  int pos = rp[d] + sl[e];
  float w = dinv[s] * dinv[d];
  csr[pos] = make_int2(s, __float_as_int(w));
}

// ============ W prep: split fp32 -> bf16 hi/lo, transpose, chunk-pack ============
// layout: Wp[kt][col][j], j in [0,32), element = W[kt*32+j][col]

__global__ __launch_bounds__(256) void k_splitW(const float* __restrict__ W1,
                                                const float* __restrict__ W2,
                                                short* __restrict__ w1h, short* __restrict__ w1l,
                                                short* __restrict__ w2h, short* __restrict__ w2l) {
  int t = blockIdx.x * 256 + threadIdx.x;
  if (t < 16384) {                       // W1: 128 x 128
    int k = t >> 7, c = t & 127;
    float v = W1[t];
    short h = bf_hi(v), l = bf_hi(v - bf_f(h));
    int idx = (((k >> 5) * 128 + c) << 5) | (k & 31);
    w1h[idx] = h; w1l[idx] = l;
  } else if (t < 16384 + 8192) {         // W2: 128 x 64
    int u = t - 16384;
    int k = u >> 6, c = u & 63;
    float v = W2[u];
    short h = bf_hi(v), l = bf_hi(v - bf_f(h));
    int idx = (((k >> 5) * 64 + c) << 5) | (k & 31);
    w2h[idx] = h; w2l[idx] = l;
  }
}

// ============ GEMM via bf16-split MFMA, row-blocked R=4, column-tiled ============
// wave = 64 rows x (NCT*16) cols; blockIdx.y = column tile. Grid doubled vs
// full-width for occupancy (was 6.9% at 391 blocks); B-reuse per load stays 16 MFMAs.

template<int COUT, int NCT>
__global__ __launch_bounds__(256) void k_gemm_mfma(const float* __restrict__ X,
                                                   const short* __restrict__ Wh,
                                                   const short* __restrict__ Wl,
                                                   float* __restrict__ XW, int Nrows) {
  constexpr int R = 4;
  const int lane = threadIdx.x & 63;
  const int wv = threadIdx.x >> 6;
  const int m0 = blockIdx.x * (64 * R) + wv * (16 * R);
  const int cbase = blockIdx.y * (NCT * 16);   // column-tile origin
  const int fr = lane & 15;   // A row / B col index
  const int g  = lane >> 4;   // k-group (8 bf16 each)

  const float* xp[R];
#pragma unroll
  for (int r = 0; r < R; ++r) {
    int arow = m0 + r * 16 + fr; if (arow > Nrows - 1) arow = Nrows - 1;
    xp[r] = X + (size_t)arow * 128 + g * 8;
  }

  f32x4 acc[R][NCT];
#pragma unroll
  for (int r = 0; r < R; ++r)
#pragma unroll
    for (int ct = 0; ct < NCT; ++ct) acc[r][ct] = (f32x4){0.f, 0.f, 0.f, 0.f};

#pragma unroll
  for (int kt = 0; kt < 4; ++kt) {
    short8v ahi[R], alo[R];
#pragma unroll
    for (int r = 0; r < R; ++r) {
      float4 xa = *reinterpret_cast<const float4*>(xp[r] + kt * 32);
      float4 xb = *reinterpret_cast<const float4*>(xp[r] + kt * 32 + 4);
      float xs[8] = {xa.x, xa.y, xa.z, xa.w, xb.x, xb.y, xb.z, xb.w};
#pragma unroll
      for (int i = 0; i < 8; ++i) {
        short h = bf_hi(xs[i]);
        ahi[r][i] = h;
        alo[r][i] = bf_hi(xs[i] - bf_f(h));
      }
    }
    const short* wb  = Wh + ((kt * COUT + cbase + fr) << 5) + g * 8;
    const short* wlb = Wl + ((kt * COUT + cbase + fr) << 5) + g * 8;
#pragma unroll
    for (int ct = 0; ct < NCT; ++ct) {
      short8v bhi = *reinterpret_cast<const short8v*>(wb  + (ct << 9));
      short8v blo = *reinterpret_cast<const short8v*>(wlb + (ct << 9));
#pragma unroll
      for (int r = 0; r < R; ++r) {
        acc[r][ct] = __builtin_amdgcn_mfma_f32_16x16x32_bf16(alo[r], blo, acc[r][ct], 0, 0, 0);
        acc[r][ct] = __builtin_amdgcn_mfma_f32_16x16x32_bf16(alo[r], bhi, acc[r][ct], 0, 0, 0);
        acc[r][ct] = __builtin_amdgcn_mfma_f32_16x16x32_bf16(ahi[r], blo, acc[r][ct], 0, 0, 0);
        acc[r][ct] = __builtin_amdgcn_mfma_f32_16x16x32_bf16(ahi[r], bhi, acc[r][ct], 0, 0, 0);
      }
    }
  }
  // D: row = r*16 + g*4 + j, col = cbase + ct*16 + fr   [m89/m91 verified]
#pragma unroll
  for (int r = 0; r < R; ++r) {
    const int orow = m0 + r * 16 + g * 4;
#pragma unroll
    for (int ct = 0; ct < NCT; ++ct) {
#pragma unroll
      for (int j = 0; j < 4; ++j) {
        int rr = orow + j;
        if (rr < Nrows) XW[(size_t)rr * COUT + cbase + (ct << 4) + fr] = acc[r][ct][j];
      }
    }
  }
}

// ====== gather (C=128): h[d] = elu(b + dinv_d^2*xw[d] + sum w_j*xw[s_j]) ======

template<bool ELU_OUT>
__global__ __launch_bounds__(256) void k_gather128(const float* __restrict__ xw,
                                                   const int* __restrict__ rp,
                                                   const int2* __restrict__ csr,
                                                   const float* __restrict__ dinv,
                                                   const float* __restrict__ b,
                                                   float* __restrict__ h,
                                                   int n0, int n1) {
  int lane = threadIdx.x & 31;
  int r = n0 + blockIdx.x * 8 + (threadIdx.x >> 5);
  if (r >= n1) return;
  const float4* xw4 = reinterpret_cast<const float4*>(xw);
  float dv = dinv[r];
  float s2 = dv * dv;
  float4 bb = reinterpret_cast<const float4*>(b)[lane];
  float4 self = xw4[(size_t)r * 32 + lane];
  float4 acc;
  acc.x = bb.x + s2 * self.x;
  acc.y = bb.y + s2 * self.y;
  acc.z = bb.z + s2 * self.z;
  acc.w = bb.w + s2 * self.w;
  int j = rp[r], end = rp[r + 1];
  for (; j + 4 <= end; j += 4) {
    int2 e0 = csr[j], e1 = csr[j + 1], e2 = csr[j + 2], e3 = csr[j + 3];
    float w0 = __int_as_float(e0.y), w1 = __int_as_float(e1.y);
    float w2 = __int_as_float(e2.y), w3 = __int_as_float(e3.y);
    float4 v0 = xw4[(size_t)e0.x * 32 + lane];
    float4 v1 = xw4[(size_t)e1.x * 32 + lane];
    float4 v2 = xw4[(size_t)e2.x * 32 + lane];
    float4 v3 = xw4[(size_t)e3.x * 32 + lane];
    acc.x += w0 * v0.x + w1 * v1.x + w2 * v2.x + w3 * v3.x;
    acc.y += w0 * v0.y + w1 * v1.y + w2 * v2.y + w3 * v3.y;
    acc.z += w0 * v0.z + w1 * v1.z + w2 * v2.z + w3 * v3.z;
    acc.w += w0 * v0.w + w1 * v1.w + w2 * v2.w + w3 * v3.w;
  }
  for (; j < end; ++j) {
    int2 e = csr[j];
    float w = __int_as_float(e.y);
    float4 v = xw4[(size_t)e.x * 32 + lane];
    acc.x += w * v.x; acc.y += w * v.y; acc.z += w * v.z; acc.w += w * v.w;
  }
  if (ELU_OUT) {
    acc.x = acc.x > 0.f ? acc.x : expm1f(acc.x);
    acc.y = acc.y > 0.f ? acc.y : expm1f(acc.y);
    acc.z = acc.z > 0.f ? acc.z : expm1f(acc.z);
    acc.w = acc.w > 0.f ? acc.w : expm1f(acc.w);
  }
  reinterpret_cast<float4*>(h)[(size_t)r * 32 + lane] = acc;
}

// ====== gather (C=64) fused with elu + @W3 -> xw3[r] scalar ======

__global__ __launch_bounds__(256) void k_gather64_w3(const float* __restrict__ xw,
                                                     const int* __restrict__ rp,
                                                     const int2* __restrict__ csr,
                                                     const float* __restrict__ dinv,
                                                     const float* __restrict__ b2,
                                                     const float* __restrict__ W3,
                                                     float* __restrict__ xw3, int n) {
  int lane = threadIdx.x & 15;
  int r = blockIdx.x * 16 + (threadIdx.x >> 4);
  if (r >= n) return;
  const float4* xw4 = reinterpret_cast<const float4*>(xw);
  float dv = dinv[r];
  float s2 = dv * dv;
  float4 bb = reinterpret_cast<const float4*>(b2)[lane];
  float4 self = xw4[(size_t)r * 16 + lane];
  float4 acc;
  acc.x = bb.x + s2 * self.x;
  acc.y = bb.y + s2 * self.y;
  acc.z = bb.z + s2 * self.z;
  acc.w = bb.w + s2 * self.w;
  int j = rp[r], end = rp[r + 1];
  for (; j + 4 <= end; j += 4) {
    int2 e0 = csr[j], e1 = csr[j + 1], e2 = csr[j + 2], e3 = csr[j + 3];
    float w0 = __int_as_float(e0.y), w1 = __int_as_float(e1.y);
    float w2 = __int_as_float(e2.y), w3 = __int_as_float(e3.y);
    float4 v0 = xw4[(size_t)e0.x * 16 + lane];
    float4 v1 = xw4[(size_t)e1.x * 16 + lane];
    float4 v2 = xw4[(size_t)e2.x * 16 + lane];
    float4 v3 = xw4[(size_t)e3.x * 16 + lane];
    acc.x += w0 * v0.x + w1 * v1.x + w2 * v2.x + w3 * v3.x;
    acc.y += w0 * v0.y + w1 * v1.y + w2 * v2.y + w3 * v3.y;
    acc.z += w0 * v0.z + w1 * v1.z + w2 * v2.z + w3 * v3.z;
    acc.w += w0 * v0.w + w1 * v1.w + w2 * v2.w + w3 * v3.w;
  }
  for (; j < end; ++j) {
    int2 e = csr[j];
    float w = __int_as_float(e.y);
    float4 v = xw4[(size_t)e.x * 16 + lane];
    acc.x += w * v.x; acc.y += w * v.y; acc.z += w * v.z; acc.w += w * v.w;
  }
  acc.x = acc.x > 0.f ? acc.x : expm1f(acc.x);
  acc.y = acc.y > 0.f ? acc.y : expm1f(acc.y);
  acc.z = acc.z > 0.f ? acc.z : expm1f(acc.z);
  acc.w = acc.w > 0.f ? acc.w : expm1f(acc.w);
  float4 w3v = reinterpret_cast<const float4*>(W3)[lane];
  float p = acc.x * w3v.x + acc.y * w3v.y + acc.z * w3v.z + acc.w * w3v.w;
  p += __shfl_xor(p, 1, 16);
  p += __shfl_xor(p, 2, 16);
  p += __shfl_xor(p, 4, 16);
  p += __shfl_xor(p, 8, 16);
  if (lane == 0) xw3[r] = p;
}

// ====== gather (C=1): out[r] = b3 + dinv_r^2*xw3[r] + sum w_j*xw3[s_j] ======

__global__ __launch_bounds__(256) void k_gather1(const float* __restrict__ xw3,
                                                 const int* __restrict__ rp,
                                                 const int2* __restrict__ csr,
                                                 const float* __restrict__ dinv,
                                                 const float* __restrict__ b3,
                                                 float* __restrict__ out, int n) {
  int r = blockIdx.x * 256 + threadIdx.x;
  if (r >= n) return;
  float dv = dinv[r];
  float acc = b3[0] + dv * dv * xw3[r];
  int j = rp[r], end = rp[r + 1];
  for (; j + 4 <= end; j += 4) {
    int2 e0 = csr[j], e1 = csr[j + 1], e2 = csr[j + 2], e3 = csr[j + 3];
    acc += __int_as_float(e0.y) * xw3[e0.x] + __int_as_float(e1.y) * xw3[e1.x] +
           __int_as_float(e2.y) * xw3[e2.x] + __int_as_float(e3.y) * xw3[e3.x];
  }
  for (; j < end; ++j) {
    int2 e = csr[j];
    acc += __int_as_float(e.y) * xw3[e.x];
  }
  out[r] = acc;
}

// ================= launch =================

extern "C" void kernel_launch(void* const* d_in, const int* in_sizes, int n_in,
                              void* d_out, int out_size, void* d_ws, size_t ws_size,
                              hipStream_t stream) {
  const float* x  = (const float*)d_in[0];
  const int*   ei = (const int*)d_in[1];
  const float* W1 = (const float*)d_in[2];
  const float* b1 = (const float*)d_in[3];
  const float* W2 = (const float*)d_in[4];
  const float* b2 = (const float*)d_in[5];
  const float* W3 = (const float*)d_in[6];
  const float* b3 = (const float*)d_in[7];
  float* out = (float*)d_out;

  const int N = in_sizes[0] / 128;
  const int E = in_sizes[1] / 2;
  const int* src = ei;
  const int* dst = ei + E;

  char* ws = (char*)d_ws;
  float* dinv   = (float*)(ws + 0);                    // N f
  int*   cnt    = (int*)(ws + (512 << 10));            // N i
  int*   rp     = (int*)(ws + (1 << 20));              // N+1 i
  int*   bsum   = (int*)(ws + 3 * (512 << 10));        // <=256 i
  int*   sl     = (int*)(ws + (2 << 20));              // E i (per-edge slot)
  int2*  csr    = (int2*)(ws + (5 << 20));             // E int2 (src, w)
  short* w1h    = (short*)(ws + (11 << 20));           // 16384 bf16
  short* w1l    = w1h + 16384;
  short* w2h    = w1l + 16384;                         // 8192 bf16
  short* w2l    = w2h + 8192;
  float* bufA   = (float*)(ws + (12 << 20));           // N*128 f (xw1; later xw2)
  float* bufB   = (float*)(ws + (12 << 20) + 51200000 + 65536);  // N*128 f (h1e; later xw3)
  float* xw2 = bufA;
  float* xw3 = bufB;

  int nbN = (N + 255) / 256;
  int nbE = (E + 255) / 256;
  int gb  = (N + 255) / 256;   // 256 rows/block (R=4, 4 waves)
  int nbS = (N + SCCH - 1) / SCCH;
  int half = N / 2;

  // ---- W split/pack (independent) ----
  k_splitW<<<96, 256, 0, stream>>>(W1, W2, w1h, w1l, w2h, w2l);

  // ---- CSR build (atomic-free fill via slot trick) ----
  k_zero_i<<<nbN, 256, 0, stream>>>(cnt, N);
  k_count<<<nbE, 256, 0, stream>>>(cnt, sl, dst, E);
  k_scan1<<<nbS, 256, 0, stream>>>(cnt, rp, bsum, N);
  k_scan2<<<1, 256, 0, stream>>>(bsum, nbS);
  k_scan3<<<nbN, 256, 0, stream>>>(rp, bsum, cnt, dinv, N, E);
  k_fill<<<nbE, 256, 0, stream>>>(src, dst, sl, rp, dinv, csr, E);

  // ---- layer 1: xw1 = x@W1 (MFMA, 2 column tiles); h1e = elu(gather(xw1)) ----
  k_gemm_mfma<128, 4><<<dim3(gb, 2), 256, 0, stream>>>(x, w1h, w1l, bufA, N);
  k_gather128<true><<<(half + 7) / 8, 256, 0, stream>>>(bufA, rp, csr, dinv, b1, bufB, 0, half);
  k_gather128<true><<<(N - half + 7) / 8, 256, 0, stream>>>(bufA, rp, csr, dinv, b1, bufB, half, N);

  // ---- layer 2: xw2 = h1e@W2 (MFMA, 2 column tiles); xw3 = elu(gather(xw2)) @ W3 ----
  k_gemm_mfma<64, 2><<<dim3(gb, 2), 256, 0, stream>>>(bufB, w2h, w2l, xw2, N);
  k_gather64_w3<<<(N + 15) / 16, 256, 0, stream>>>(xw2, rp, csr, dinv, b2, W3, xw3, N);

  // ---- layer 3 aggregate ----
  k_gather1<<<nbN, 256, 0, stream>>>(xw3, rp, csr, dinv, b3, out, N);
}

// Round 15
// 288.832 us; speedup vs baseline: 1.0307x; 1.0307x over previous
//
#include <hip/hip_runtime.h>
#include <math.h>

typedef __attribute__((ext_vector_type(8))) short short8v;   // 8 x bf16 (4 VGPR)
typedef __attribute__((ext_vector_type(4))) float f32x4;     // MFMA acc

__device__ __forceinline__ short bf_hi(float x) {
  union { float f; unsigned u; } c; c.f = x;
  unsigned r = (c.u + 0x7fffu + ((c.u >> 16) & 1u)) >> 16;   // RNE bf16
  return (short)r;
}
__device__ __forceinline__ float bf_f(short h) {
  union { float f; unsigned u; } c; c.u = ((unsigned)(unsigned short)h) << 16;
  return c.f;
}

// ================= CSR build =================

__global__ __launch_bounds__(256) void k_zero_i(int* __restrict__ p, int n) {
  int i = blockIdx.x * 256 + threadIdx.x;
  if (i < n) p[i] = 0;
}

// count degrees AND record each edge's slot within its dst bucket (coalesced write)
__global__ __launch_bounds__(256) void k_count(int* __restrict__ cnt,
                                               int* __restrict__ sl,
                                               const int* __restrict__ dst, int E) {
  int e = blockIdx.x * 256 + threadIdx.x;
  if (e < E) sl[e] = atomicAdd(&cnt[dst[e]], 1);
}

constexpr int SCI = 8, SCCH = 2048;  // 256 threads * 8 items

__global__ __launch_bounds__(256) void k_scan1(const int* __restrict__ cnt,
                                               int* __restrict__ rp,
                                               int* __restrict__ bsum, int n) {
  __shared__ int sh[256];
  int tid = threadIdx.x;
  int base = blockIdx.x * SCCH + tid * SCI;
  int v[SCI];
  int s = 0;
#pragma unroll
  for (int i = 0; i < SCI; ++i) { int idx = base + i; v[i] = (idx < n) ? cnt[idx] : 0; s += v[i]; }
  sh[tid] = s;
  __syncthreads();
  for (int off = 1; off < 256; off <<= 1) {
    int t = (tid >= off) ? sh[tid - off] : 0;
    __syncthreads();
    sh[tid] += t;
    __syncthreads();
  }
  int excl = sh[tid] - s;
  if (tid == 255) bsum[blockIdx.x] = sh[255];
  int run = excl;
#pragma unroll
  for (int i = 0; i < SCI; ++i) { int idx = base + i; if (idx < n) rp[idx] = run; run += v[i]; }
}

__global__ __launch_bounds__(256) void k_scan2(int* __restrict__ bsum, int nb) {
  __shared__ int sh[256];
  int tid = threadIdx.x;
  int s = (tid < nb) ? bsum[tid] : 0;
  sh[tid] = s;
  __syncthreads();
  for (int off = 1; off < 256; off <<= 1) {
    int t = (tid >= off) ? sh[tid - off] : 0;
    __syncthreads();
    sh[tid] += t;
    __syncthreads();
  }
  if (tid < nb) bsum[tid] = sh[tid] - s;  // exclusive
}

// rp finalize + dinv, fused
__global__ __launch_bounds__(256) void k_scan3(int* __restrict__ rp,
                                               const int* __restrict__ bsum,
                                               const int* __restrict__ cnt_in,
                                               float* __restrict__ dinv,
                                               int n, int Etot) {
  int i = blockIdx.x * 256 + threadIdx.x;
  if (i < n) {
    rp[i] = rp[i] + bsum[i / SCCH];
    dinv[i] = rsqrtf(1.0f + (float)cnt_in[i]);  // +1 self-loop
  }
  if (i == 0) rp[n] = Etot;
}

// fill csr entries (src, w) with no atomics: pos = rp[dst] + slot
__global__ __launch_bounds__(256) void k_fill(const int* __restrict__ src,
                                              const int* __restrict__ dst,
                                              const int* __restrict__ sl,
                                              const int* __restrict__ rp,
                                              const float* __restrict__ dinv,
                                              int2* __restrict__ csr, int E) {
  int e = blockIdx.x * 256 + threadIdx.x;
  if (e >= E) return;
  int s = src[e], d = dst[e];
  int pos = rp[d] + sl[e];
  float w = dinv[s] * dinv[d];
  csr[pos] = make_int2(s, __float_as_int(w));
}

// ============ W prep: split fp32 -> bf16 hi/lo, transpose, chunk-pack ============
// layout: Wp[kt][col][j], j in [0,32), element = W[kt*32+j][col]

__global__ __launch_bounds__(256) void k_splitW(const float* __restrict__ W1,
                                                const float* __restrict__ W2,
                                                short* __restrict__ w1h, short* __restrict__ w1l,
                                                short* __restrict__ w2h, short* __restrict__ w2l) {
  int t = blockIdx.x * 256 + threadIdx.x;
  if (t < 16384) {                       // W1: 128 x 128
    int k = t >> 7, c = t & 127;
    float v = W1[t];
    short h = bf_hi(v), l = bf_hi(v - bf_f(h));
    int idx = (((k >> 5) * 128 + c) << 5) | (k & 31);
    w1h[idx] = h; w1l[idx] = l;
  } else if (t < 16384 + 8192) {         // W2: 128 x 64
    int u = t - 16384;
    int k = u >> 6, c = u & 63;
    float v = W2[u];
    short h = bf_hi(v), l = bf_hi(v - bf_f(h));
    int idx = (((k >> 5) * 64 + c) << 5) | (k & 31);
    w2h[idx] = h; w2l[idx] = l;
  }
}

// ============ GEMM via bf16-split MFMA, row-blocked R=4 (round-12 config) ============

template<int COUT>
__global__ __launch_bounds__(256) void k_gemm_mfma(const float* __restrict__ X,
                                                   const short* __restrict__ Wh,
                                                   const short* __restrict__ Wl,
                                                   float* __restrict__ XW, int Nrows) {
  constexpr int NCT = COUT / 16;
  constexpr int R = 4;
  const int lane = threadIdx.x & 63;
  const int wv = threadIdx.x >> 6;
  const int m0 = blockIdx.x * (64 * R) + wv * (16 * R);
  const int fr = lane & 15;   // A row / B col index
  const int g  = lane >> 4;   // k-group (8 bf16 each)

  const float* xp[R];
#pragma unroll
  for (int r = 0; r < R; ++r) {
    int arow = m0 + r * 16 + fr; if (arow > Nrows - 1) arow = Nrows - 1;
    xp[r] = X + (size_t)arow * 128 + g * 8;
  }

  f32x4 acc[R][NCT];
#pragma unroll
  for (int r = 0; r < R; ++r)
#pragma unroll
    for (int ct = 0; ct < NCT; ++ct) acc[r][ct] = (f32x4){0.f, 0.f, 0.f, 0.f};

#pragma unroll
  for (int kt = 0; kt < 4; ++kt) {
    short8v ahi[R], alo[R];
#pragma unroll
    for (int r = 0; r < R; ++r) {
      float4 xa = *reinterpret_cast<const float4*>(xp[r] + kt * 32);
      float4 xb = *reinterpret_cast<const float4*>(xp[r] + kt * 32 + 4);
      float xs[8] = {xa.x, xa.y, xa.z, xa.w, xb.x, xb.y, xb.z, xb.w};
#pragma unroll
      for (int i = 0; i < 8; ++i) {
        short h = bf_hi(xs[i]);
        ahi[r][i] = h;
        alo[r][i] = bf_hi(xs[i] - bf_f(h));
      }
    }
    const short* wb  = Wh + ((kt * COUT + fr) << 5) + g * 8;
    const short* wlb = Wl + ((kt * COUT + fr) << 5) + g * 8;
#pragma unroll
    for (int ct = 0; ct < NCT; ++ct) {
      short8v bhi = *reinterpret_cast<const short8v*>(wb  + (ct << 9));
      short8v blo = *reinterpret_cast<const short8v*>(wlb + (ct << 9));
#pragma unroll
      for (int r = 0; r < R; ++r) {
        acc[r][ct] = __builtin_amdgcn_mfma_f32_16x16x32_bf16(alo[r], blo, acc[r][ct], 0, 0, 0);
        acc[r][ct] = __builtin_amdgcn_mfma_f32_16x16x32_bf16(alo[r], bhi, acc[r][ct], 0, 0, 0);
        acc[r][ct] = __builtin_amdgcn_mfma_f32_16x16x32_bf16(ahi[r], blo, acc[r][ct], 0, 0, 0);
        acc[r][ct] = __builtin_amdgcn_mfma_f32_16x16x32_bf16(ahi[r], bhi, acc[r][ct], 0, 0, 0);
      }
    }
  }
  // D: row = r*16 + g*4 + j, col = ct*16 + fr   [m89/m91 verified]
#pragma unroll
  for (int r = 0; r < R; ++r) {
    const int orow = m0 + r * 16 + g * 4;
#pragma unroll
    for (int ct = 0; ct < NCT; ++ct) {
#pragma unroll
      for (int j = 0; j < 4; ++j) {
        int rr = orow + j;
        if (rr < Nrows) XW[(size_t)rr * COUT + (ct << 4) + fr] = acc[r][ct][j];
      }
    }
  }
}

// ====== gather (C=128): h[d] = elu(b + dinv_d^2*xw[d] + sum w_j*xw[s_j]) ======
// unroll 8: 8 independent csr + 8 independent row loads in flight per lane

template<bool ELU_OUT>
__global__ __launch_bounds__(256) void k_gather128(const float* __restrict__ xw,
                                                   const int* __restrict__ rp,
                                                   const int2* __restrict__ csr,
                                                   const float* __restrict__ dinv,
                                                   const float* __restrict__ b,
                                                   float* __restrict__ h, int n) {
  int lane = threadIdx.x & 31;
  int r = blockIdx.x * 8 + (threadIdx.x >> 5);
  if (r >= n) return;
  const float4* xw4 = reinterpret_cast<const float4*>(xw);
  float dv = dinv[r];
  float s2 = dv * dv;
  float4 bb = reinterpret_cast<const float4*>(b)[lane];
  float4 self = xw4[(size_t)r * 32 + lane];
  float4 acc;
  acc.x = bb.x + s2 * self.x;
  acc.y = bb.y + s2 * self.y;
  acc.z = bb.z + s2 * self.z;
  acc.w = bb.w + s2 * self.w;
  int j = rp[r], end = rp[r + 1];
  for (; j + 8 <= end; j += 8) {
    int2 e[8];
#pragma unroll
    for (int q = 0; q < 8; ++q) e[q] = csr[j + q];
    float4 v[8];
#pragma unroll
    for (int q = 0; q < 8; ++q) v[q] = xw4[(size_t)e[q].x * 32 + lane];
#pragma unroll
    for (int q = 0; q < 8; ++q) {
      float w = __int_as_float(e[q].y);
      acc.x += w * v[q].x; acc.y += w * v[q].y;
      acc.z += w * v[q].z; acc.w += w * v[q].w;
    }
  }
  for (; j + 4 <= end; j += 4) {
    int2 e0 = csr[j], e1 = csr[j + 1], e2 = csr[j + 2], e3 = csr[j + 3];
    float w0 = __int_as_float(e0.y), w1 = __int_as_float(e1.y);
    float w2 = __int_as_float(e2.y), w3 = __int_as_float(e3.y);
    float4 v0 = xw4[(size_t)e0.x * 32 + lane];
    float4 v1 = xw4[(size_t)e1.x * 32 + lane];
    float4 v2 = xw4[(size_t)e2.x * 32 + lane];
    float4 v3 = xw4[(size_t)e3.x * 32 + lane];
    acc.x += w0 * v0.x + w1 * v1.x + w2 * v2.x + w3 * v3.x;
    acc.y += w0 * v0.y + w1 * v1.y + w2 * v2.y + w3 * v3.y;
    acc.z += w0 * v0.z + w1 * v1.z + w2 * v2.z + w3 * v3.z;
    acc.w += w0 * v0.w + w1 * v1.w + w2 * v2.w + w3 * v3.w;
  }
  for (; j < end; ++j) {
    int2 e = csr[j];
    float w = __int_as_float(e.y);
    float4 v = xw4[(size_t)e.x * 32 + lane];
    acc.x += w * v.x; acc.y += w * v.y; acc.z += w * v.z; acc.w += w * v.w;
  }
  if (ELU_OUT) {
    acc.x = acc.x > 0.f ? acc.x : expm1f(acc.x);
    acc.y = acc.y > 0.f ? acc.y : expm1f(acc.y);
    acc.z = acc.z > 0.f ? acc.z : expm1f(acc.z);
    acc.w = acc.w > 0.f ? acc.w : expm1f(acc.w);
  }
  reinterpret_cast<float4*>(h)[(size_t)r * 32 + lane] = acc;
}

// ====== gather (C=64) fused with elu + @W3 -> xw3[r] scalar ======

__global__ __launch_bounds__(256) void k_gather64_w3(const float* __restrict__ xw,
                                                     const int* __restrict__ rp,
                                                     const int2* __restrict__ csr,
                                                     const float* __restrict__ dinv,
                                                     const float* __restrict__ b2,
                                                     const float* __restrict__ W3,
                                                     float* __restrict__ xw3, int n) {
  int lane = threadIdx.x & 15;
  int r = blockIdx.x * 16 + (threadIdx.x >> 4);
  if (r >= n) return;
  const float4* xw4 = reinterpret_cast<const float4*>(xw);
  float dv = dinv[r];
  float s2 = dv * dv;
  float4 bb = reinterpret_cast<const float4*>(b2)[lane];
  float4 self = xw4[(size_t)r * 16 + lane];
  float4 acc;
  acc.x = bb.x + s2 * self.x;
  acc.y = bb.y + s2 * self.y;
  acc.z = bb.z + s2 * self.z;
  acc.w = bb.w + s2 * self.w;
  int j = rp[r], end = rp[r + 1];
  for (; j + 4 <= end; j += 4) {
    int2 e0 = csr[j], e1 = csr[j + 1], e2 = csr[j + 2], e3 = csr[j + 3];
    float w0 = __int_as_float(e0.y), w1 = __int_as_float(e1.y);
    float w2 = __int_as_float(e2.y), w3 = __int_as_float(e3.y);
    float4 v0 = xw4[(size_t)e0.x * 16 + lane];
    float4 v1 = xw4[(size_t)e1.x * 16 + lane];
    float4 v2 = xw4[(size_t)e2.x * 16 + lane];
    float4 v3 = xw4[(size_t)e3.x * 16 + lane];
    acc.x += w0 * v0.x + w1 * v1.x + w2 * v2.x + w3 * v3.x;
    acc.y += w0 * v0.y + w1 * v1.y + w2 * v2.y + w3 * v3.y;
    acc.z += w0 * v0.z + w1 * v1.z + w2 * v2.z + w3 * v3.z;
    acc.w += w0 * v0.w + w1 * v1.w + w2 * v2.w + w3 * v3.w;
  }
  for (; j < end; ++j) {
    int2 e = csr[j];
    float w = __int_as_float(e.y);
    float4 v = xw4[(size_t)e.x * 16 + lane];
    acc.x += w * v.x; acc.y += w * v.y; acc.z += w * v.z; acc.w += w * v.w;
  }
  acc.x = acc.x > 0.f ? acc.x : expm1f(acc.x);
  acc.y = acc.y > 0.f ? acc.y : expm1f(acc.y);
  acc.z = acc.z > 0.f ? acc.z : expm1f(acc.z);
  acc.w = acc.w > 0.f ? acc.w : expm1f(acc.w);
  float4 w3v = reinterpret_cast<const float4*>(W3)[lane];
  float p = acc.x * w3v.x + acc.y * w3v.y + acc.z * w3v.z + acc.w * w3v.w;
  p += __shfl_xor(p, 1, 16);
  p += __shfl_xor(p, 2, 16);
  p += __shfl_xor(p, 4, 16);
  p += __shfl_xor(p, 8, 16);
  if (lane == 0) xw3[r] = p;
}

// ====== gather (C=1): out[r] = b3 + dinv_r^2*xw3[r] + sum w_j*xw3[s_j] ======

__global__ __launch_bounds__(256) void k_gather1(const float* __restrict__ xw3,
                                                 const int* __restrict__ rp,
                                                 const int2* __restrict__ csr,
                                                 const float* __restrict__ dinv,
                                                 const float* __restrict__ b3,
                                                 float* __restrict__ out, int n) {
  int r = blockIdx.x * 256 + threadIdx.x;
  if (r >= n) return;
  float dv = dinv[r];
  float acc = b3[0] + dv * dv * xw3[r];
  int j = rp[r], end = rp[r + 1];
  for (; j + 4 <= end; j += 4) {
    int2 e0 = csr[j], e1 = csr[j + 1], e2 = csr[j + 2], e3 = csr[j + 3];
    acc += __int_as_float(e0.y) * xw3[e0.x] + __int_as_float(e1.y) * xw3[e1.x] +
           __int_as_float(e2.y) * xw3[e2.x] + __int_as_float(e3.y) * xw3[e3.x];
  }
  for (; j < end; ++j) {
    int2 e = csr[j];
    acc += __int_as_float(e.y) * xw3[e.x];
  }
  out[r] = acc;
}

// ================= launch =================

extern "C" void kernel_launch(void* const* d_in, const int* in_sizes, int n_in,
                              void* d_out, int out_size, void* d_ws, size_t ws_size,
                              hipStream_t stream) {
  const float* x  = (const float*)d_in[0];
  const int*   ei = (const int*)d_in[1];
  const float* W1 = (const float*)d_in[2];
  const float* b1 = (const float*)d_in[3];
  const float* W2 = (const float*)d_in[4];
  const float* b2 = (const float*)d_in[5];
  const float* W3 = (const float*)d_in[6];
  const float* b3 = (const float*)d_in[7];
  float* out = (float*)d_out;

  const int N = in_sizes[0] / 128;
  const int E = in_sizes[1] / 2;
  const int* src = ei;
  const int* dst = ei + E;

  char* ws = (char*)d_ws;
  float* dinv   = (float*)(ws + 0);                    // N f
  int*   cnt    = (int*)(ws + (512 << 10));            // N i
  int*   rp     = (int*)(ws + (1 << 20));              // N+1 i
  int*   bsum   = (int*)(ws + 3 * (512 << 10));        // <=256 i
  int*   sl     = (int*)(ws + (2 << 20));              // E i (per-edge slot)
  int2*  csr    = (int2*)(ws + (5 << 20));             // E int2 (src, w)
  short* w1h    = (short*)(ws + (11 << 20));           // 16384 bf16
  short* w1l    = w1h + 16384;
  short* w2h    = w1l + 16384;                         // 8192 bf16
  short* w2l    = w2h + 8192;
  float* bufA   = (float*)(ws + (12 << 20));           // N*128 f (xw1; later xw2)
  float* bufB   = (float*)(ws + (12 << 20) + 51200000 + 65536);  // N*128 f (h1e; later xw3)
  float* xw2 = bufA;
  float* xw3 = bufB;

  int nbN = (N + 255) / 256;
  int nbE = (E + 255) / 256;
  int gb  = (N + 255) / 256;   // 256 rows/block (R=4, 4 waves)
  int nbS = (N + SCCH - 1) / SCCH;

  // ---- W split/pack (independent) ----
  k_splitW<<<96, 256, 0, stream>>>(W1, W2, w1h, w1l, w2h, w2l);

  // ---- CSR build (atomic-free fill via slot trick) ----
  k_zero_i<<<nbN, 256, 0, stream>>>(cnt, N);
  k_count<<<nbE, 256, 0, stream>>>(cnt, sl, dst, E);
  k_scan1<<<nbS, 256, 0, stream>>>(cnt, rp, bsum, N);
  k_scan2<<<1, 256, 0, stream>>>(bsum, nbS);
  k_scan3<<<nbN, 256, 0, stream>>>(rp, bsum, cnt, dinv, N, E);
  k_fill<<<nbE, 256, 0, stream>>>(src, dst, sl, rp, dinv, csr, E);

  // ---- layer 1: xw1 = x@W1 (MFMA); h1e = elu(gather(xw1)) ----
  k_gemm_mfma<128><<<gb, 256, 0, stream>>>(x, w1h, w1l, bufA, N);
  k_gather128<true><<<(N + 7) / 8, 256, 0, stream>>>(bufA, rp, csr, dinv, b1, bufB, N);

  // ---- layer 2: xw2 = h1e@W2 (MFMA); xw3 = elu(gather(xw2)) @ W3 (fused) ----
  k_gemm_mfma<64><<<gb, 256, 0, stream>>>(bufB, w2h, w2l, xw2, N);
  k_gather64_w3<<<(N + 15) / 16, 256, 0, stream>>>(xw2, rp, csr, dinv, b2, W3, xw3, N);

  // ---- layer 3 aggregate ----
  k_gather1<<<nbN, 256, 0, stream>>>(xw3, rp, csr, dinv, b3, out, N);
}